// Round 3
// baseline (201.356 us; speedup 1.0000x reference)
//
#include <hip/hip_runtime.h>
#include <hip/hip_bf16.h>

// DeepLinearNet: out = x @ (W_0^T W_1^T ... W_63^T), x:(8388608,3) fp32, W:(64,3,3) fp32.
// Collapse the 64-layer chain into one 3x3 matrix P (fp64 tree-fold kernel),
// then apply P in a streaming kernel. R3: persistent-ish blocks (2048 = 8/CU),
// 4 row-groups per thread with all 12 loads issued before any use (deep MLP),
// nontemporal stores. LDS staging removed (R2 proved pattern-neutral).

#define DEPTH 64
#define BLOCK 256
#define GPT 4                 // row-groups (3 float4s) per thread

typedef float vf4 __attribute__((ext_vector_type(4)));

// ---- Kernel A: parallel fold. 64 threads each load one W_l, then a 6-step
// order-preserving product tree in LDS (fp64). ----
__global__ __launch_bounds__(64) void fold_weights(const float* __restrict__ W,
                                                   float* __restrict__ P) {
    __shared__ double M[DEPTH][9];
    const int t = threadIdx.x;  // 0..63, single wave
    const float* Wl = W + t * 9;
    #pragma unroll
    for (int k = 0; k < 3; ++k)
        #pragma unroll
        for (int j = 0; j < 3; ++j)
            M[t][k * 3 + j] = (double)Wl[j * 3 + k];   // M_t = W_t^T
    __syncthreads();
    for (int s = 1; s < DEPTH; s <<= 1) {
        if ((t & (2 * s - 1)) == 0) {
            double a[9], b[9], c[9];
            #pragma unroll
            for (int i = 0; i < 9; ++i) { a[i] = M[t][i]; b[i] = M[t + s][i]; }
            #pragma unroll
            for (int i = 0; i < 3; ++i)
                #pragma unroll
                for (int j = 0; j < 3; ++j)
                    c[i * 3 + j] = a[i * 3 + 0] * b[0 * 3 + j]
                                 + a[i * 3 + 1] * b[1 * 3 + j]
                                 + a[i * 3 + 2] * b[2 * 3 + j];
            #pragma unroll
            for (int i = 0; i < 9; ++i) M[t][i] = c[i];
        }
        __syncthreads();
    }
    if (t < 9) P[t] = (float)M[0][t];   // out_j = sum_k x_k * P[k*3+j]
}

// ---- Kernel B: out[i] = x[i] @ P. 2048 blocks, 4 groups/thread, loads
// prefetched up-front for deep memory-level parallelism. ----
__global__ __launch_bounds__(BLOCK) void apply_chain(
        const vf4* __restrict__ x4, vf4* __restrict__ o4,
        const float* __restrict__ P, int n_groups) {
    const int tid = threadIdx.x;
    const int base = blockIdx.x * (BLOCK * GPT);

    // wave-uniform scalar loads -> SGPRs (issued alongside the vector loads)
    const float p00 = P[0], p01 = P[1], p02 = P[2];
    const float p10 = P[3], p11 = P[4], p12 = P[5];
    const float p20 = P[6], p21 = P[7], p22 = P[8];

    // Issue all 12 independent loads before any use (12 KB in flight per wave).
    vf4 A[GPT][3];
    #pragma unroll
    for (int k = 0; k < GPT; ++k) {
        const int g = base + k * BLOCK + tid;      // row-group index
        const vf4* p = x4 + 3 * g;                 // 3 consecutive float4s
        A[k][0] = p[0];
        A[k][1] = p[1];
        A[k][2] = p[2];
    }

    #pragma unroll
    for (int k = 0; k < GPT; ++k) {
        const int g = base + k * BLOCK + tid;
        const vf4 a = A[k][0], b = A[k][1], c = A[k][2];
        // rows: r0=(a0,a1,a2) r1=(a3,b0,b1) r2=(b2,b3,c0) r3=(c1,c2,c3)
        vf4 oa, ob, oc;
        oa[0] = fmaf(a[0], p00, fmaf(a[1], p10, a[2] * p20));
        oa[1] = fmaf(a[0], p01, fmaf(a[1], p11, a[2] * p21));
        oa[2] = fmaf(a[0], p02, fmaf(a[1], p12, a[2] * p22));
        oa[3] = fmaf(a[3], p00, fmaf(b[0], p10, b[1] * p20));
        ob[0] = fmaf(a[3], p01, fmaf(b[0], p11, b[1] * p21));
        ob[1] = fmaf(a[3], p02, fmaf(b[0], p12, b[1] * p22));
        ob[2] = fmaf(b[2], p00, fmaf(b[3], p10, c[0] * p20));
        ob[3] = fmaf(b[2], p01, fmaf(b[3], p11, c[0] * p21));
        oc[0] = fmaf(b[2], p02, fmaf(b[3], p12, c[0] * p22));
        oc[1] = fmaf(c[1], p00, fmaf(c[2], p10, c[3] * p20));
        oc[2] = fmaf(c[1], p01, fmaf(c[2], p11, c[3] * p21));
        oc[3] = fmaf(c[1], p02, fmaf(c[2], p12, c[3] * p22));
        vf4* q = o4 + 3 * g;
        __builtin_nontemporal_store(oa, q);
        __builtin_nontemporal_store(ob, q + 1);
        __builtin_nontemporal_store(oc, q + 2);
    }
}

extern "C" void kernel_launch(void* const* d_in, const int* in_sizes, int n_in,
                              void* d_out, int out_size, void* d_ws, size_t ws_size,
                              hipStream_t stream) {
    const float* x = (const float*)d_in[0];
    const float* W = (const float*)d_in[1];
    float* out = (float*)d_out;
    float* P = (float*)d_ws;                       // 9 floats of scratch

    fold_weights<<<1, 64, 0, stream>>>(W, P);

    const long long n_floats = (long long)in_sizes[0];   // 25165824
    const int n_groups = (int)(n_floats / 12);           // 2097152 row-groups
    const int grid = n_groups / (BLOCK * GPT);           // 2048 (exact fit)

    apply_chain<<<grid, BLOCK, 0, stream>>>(
        (const vf4*)x, (vf4*)out, P, n_groups);
}

// Round 4
// 182.994 us; speedup vs baseline: 1.1003x; 1.1003x over previous
//
#include <hip/hip_runtime.h>
#include <hip/hip_bf16.h>

// DeepLinearNet: out = x @ (W_0^T W_1^T ... W_63^T), x:(8388608,3) fp32, W:(64,3,3) fp32.
// Collapse the 64-layer chain into one 3x3 matrix P (fp64 tree-fold kernel),
// then apply P in a streaming kernel.
// R4: persistent grid-stride kernel (1024 blocks = 4/CU, 8 iterations/thread)
// with software-pipelined prefetch; PLAIN stores (R3's nontemporal stores
// inflated WRITE_SIZE 100->136 MB and regressed 60->78 us).

#define DEPTH 64
#define BLOCK 256
#define GRID  1024            // 4 blocks/CU, 16 waves/CU; 8 iters/thread exact

typedef float vf4 __attribute__((ext_vector_type(4)));

// ---- Kernel A: parallel fold. 64 threads each load one W_l, then a 6-step
// order-preserving product tree in LDS (fp64). ----
__global__ __launch_bounds__(64) void fold_weights(const float* __restrict__ W,
                                                   float* __restrict__ P) {
    __shared__ double M[DEPTH][9];
    const int t = threadIdx.x;  // 0..63, single wave
    const float* Wl = W + t * 9;
    #pragma unroll
    for (int k = 0; k < 3; ++k)
        #pragma unroll
        for (int j = 0; j < 3; ++j)
            M[t][k * 3 + j] = (double)Wl[j * 3 + k];   // M_t = W_t^T
    __syncthreads();
    for (int s = 1; s < DEPTH; s <<= 1) {
        if ((t & (2 * s - 1)) == 0) {
            double a[9], b[9], c[9];
            #pragma unroll
            for (int i = 0; i < 9; ++i) { a[i] = M[t][i]; b[i] = M[t + s][i]; }
            #pragma unroll
            for (int i = 0; i < 3; ++i)
                #pragma unroll
                for (int j = 0; j < 3; ++j)
                    c[i * 3 + j] = a[i * 3 + 0] * b[0 * 3 + j]
                                 + a[i * 3 + 1] * b[1 * 3 + j]
                                 + a[i * 3 + 2] * b[2 * 3 + j];
            #pragma unroll
            for (int i = 0; i < 9; ++i) M[t][i] = c[i];
        }
        __syncthreads();
    }
    if (t < 9) P[t] = (float)M[0][t];   // out_j = sum_k x_k * P[k*3+j]
}

// ---- Kernel B: out[i] = x[i] @ P. Persistent grid-stride, double-buffered
// prefetch: next unit's 3 loads are in flight while current unit stores. ----
__global__ __launch_bounds__(BLOCK) void apply_chain(
        const vf4* __restrict__ x4, vf4* __restrict__ o4,
        const float* __restrict__ P, long long n_units) {
    // wave-uniform scalar loads -> SGPRs
    const float p00 = P[0], p01 = P[1], p02 = P[2];
    const float p10 = P[3], p11 = P[4], p12 = P[5];
    const float p20 = P[6], p21 = P[7], p22 = P[8];

    const long long stride = (long long)GRID * BLOCK;
    long long u = (long long)blockIdx.x * BLOCK + threadIdx.x;

    const vf4* p = x4 + 3 * u;
    vf4 a = p[0], b = p[1], c = p[2];

    while (true) {
        const long long un = u + stride;
        const bool more = un < n_units;
        vf4 na, nb, nc;
        if (more) {                       // prefetch next unit (3 loads issued
            const vf4* q = x4 + 3 * un;   //  before this unit's stores)
            na = q[0]; nb = q[1]; nc = q[2];
        }

        // rows: r0=(a0,a1,a2) r1=(a3,b0,b1) r2=(b2,b3,c0) r3=(c1,c2,c3)
        vf4 oa, ob, oc;
        oa[0] = fmaf(a[0], p00, fmaf(a[1], p10, a[2] * p20));
        oa[1] = fmaf(a[0], p01, fmaf(a[1], p11, a[2] * p21));
        oa[2] = fmaf(a[0], p02, fmaf(a[1], p12, a[2] * p22));
        oa[3] = fmaf(a[3], p00, fmaf(b[0], p10, b[1] * p20));
        ob[0] = fmaf(a[3], p01, fmaf(b[0], p11, b[1] * p21));
        ob[1] = fmaf(a[3], p02, fmaf(b[0], p12, b[1] * p22));
        ob[2] = fmaf(b[2], p00, fmaf(b[3], p10, c[0] * p20));
        ob[3] = fmaf(b[2], p01, fmaf(b[3], p11, c[0] * p21));
        oc[0] = fmaf(b[2], p02, fmaf(b[3], p12, c[0] * p22));
        oc[1] = fmaf(c[1], p00, fmaf(c[2], p10, c[3] * p20));
        oc[2] = fmaf(c[1], p01, fmaf(c[2], p11, c[3] * p21));
        oc[3] = fmaf(c[1], p02, fmaf(c[2], p12, c[3] * p22));

        vf4* w = o4 + 3 * u;
        w[0] = oa; w[1] = ob; w[2] = oc;

        if (!more) break;
        u = un; a = na; b = nb; c = nc;
    }
}

extern "C" void kernel_launch(void* const* d_in, const int* in_sizes, int n_in,
                              void* d_out, int out_size, void* d_ws, size_t ws_size,
                              hipStream_t stream) {
    const float* x = (const float*)d_in[0];
    const float* W = (const float*)d_in[1];
    float* out = (float*)d_out;
    float* P = (float*)d_ws;                       // 9 floats of scratch

    fold_weights<<<1, 64, 0, stream>>>(W, P);

    const long long n_floats = (long long)in_sizes[0];   // 25165824
    const long long n_units = n_floats / 12;             // 2097152 (4-row units)
    // 1024 blocks x 256 threads x 8 iterations = 2097152: exact fit

    apply_chain<<<GRID, BLOCK, 0, stream>>>(
        (const vf4*)x, (vf4*)out, P, n_units);
}

// Round 5
// 179.405 us; speedup vs baseline: 1.1224x; 1.0200x over previous
//
#include <hip/hip_runtime.h>
#include <hip/hip_bf16.h>

// DeepLinearNet: out = x @ (W_0^T W_1^T ... W_63^T), x:(8388608,3) fp32, W:(64,3,3) fp32.
// R5: single fused kernel. Each block:
//   1. issues its 12 data loads (48 B x 256 threads, all independent, up front)
//   2. redundantly folds the 64 3x3 matrices into P (fp64 LDS tree; W is 576 B,
//      L2-resident after the first blocks) -- fold latency hides the data loads
//   3. computes out = row @ P and stores with plain dwordx4
// History: R1 strided(60us) == R2 LDS-coalesced(60) == R4 persistent+prefetch(61-63);
// R3's nt stores inflated WRITE 100->136MB and regressed (78). Shape-invariant
// ~60us => ~3.3 TB/s request-side cap; this round removes the fold launch and
// tests deep up-front MLP without the nt confound.

#define DEPTH 64
#define BLOCK 256
#define GRID  2048
#define GPT   4               // row-group units (3 float4s) per thread

typedef float vf4 __attribute__((ext_vector_type(4)));

__global__ __launch_bounds__(BLOCK) void deep_linear(
        const float* __restrict__ W, const vf4* __restrict__ x4,
        vf4* __restrict__ o4) {
    __shared__ double M[DEPTH][9];
    __shared__ float Ps[9];
    const int tid = threadIdx.x;
    const int base = blockIdx.x * (BLOCK * GPT);

    // ---- 1. issue all 12 independent data loads up front ----
    vf4 A[GPT][3];
    #pragma unroll
    for (int k = 0; k < GPT; ++k) {
        const vf4* p = x4 + 3 * (base + k * BLOCK + tid);
        A[k][0] = p[0];
        A[k][1] = p[1];
        A[k][2] = p[2];
    }

    // ---- 2. in-block fold: P = W_0^T W_1^T ... W_63^T (fp64 tree) ----
    if (tid < DEPTH) {
        const float* Wl = W + tid * 9;
        #pragma unroll
        for (int kk = 0; kk < 3; ++kk)
            #pragma unroll
            for (int j = 0; j < 3; ++j)
                M[tid][kk * 3 + j] = (double)Wl[j * 3 + kk];   // M_t = W_t^T
    }
    __syncthreads();
    #pragma unroll
    for (int s = 1; s < DEPTH; s <<= 1) {
        if (tid < DEPTH && (tid & (2 * s - 1)) == 0) {
            double a[9], b[9], c[9];
            #pragma unroll
            for (int i = 0; i < 9; ++i) { a[i] = M[tid][i]; b[i] = M[tid + s][i]; }
            #pragma unroll
            for (int i = 0; i < 3; ++i)
                #pragma unroll
                for (int j = 0; j < 3; ++j)
                    c[i * 3 + j] = a[i * 3 + 0] * b[0 * 3 + j]
                                 + a[i * 3 + 1] * b[1 * 3 + j]
                                 + a[i * 3 + 2] * b[2 * 3 + j];
            #pragma unroll
            for (int i = 0; i < 9; ++i) M[tid][i] = c[i];
        }
        __syncthreads();
    }
    if (tid < 9) Ps[tid] = (float)M[0][tid];   // out_j = sum_k x_k * P[k*3+j]
    __syncthreads();

    const float p00 = Ps[0], p01 = Ps[1], p02 = Ps[2];
    const float p10 = Ps[3], p11 = Ps[4], p12 = Ps[5];
    const float p20 = Ps[6], p21 = Ps[7], p22 = Ps[8];

    // ---- 3. compute + plain coalesced-width stores ----
    #pragma unroll
    for (int k = 0; k < GPT; ++k) {
        const vf4 a = A[k][0], b = A[k][1], c = A[k][2];
        // rows: r0=(a0,a1,a2) r1=(a3,b0,b1) r2=(b2,b3,c0) r3=(c1,c2,c3)
        vf4 oa, ob, oc;
        oa[0] = fmaf(a[0], p00, fmaf(a[1], p10, a[2] * p20));
        oa[1] = fmaf(a[0], p01, fmaf(a[1], p11, a[2] * p21));
        oa[2] = fmaf(a[0], p02, fmaf(a[1], p12, a[2] * p22));
        oa[3] = fmaf(a[3], p00, fmaf(b[0], p10, b[1] * p20));
        ob[0] = fmaf(a[3], p01, fmaf(b[0], p11, b[1] * p21));
        ob[1] = fmaf(a[3], p02, fmaf(b[0], p12, b[1] * p22));
        ob[2] = fmaf(b[2], p00, fmaf(b[3], p10, c[0] * p20));
        ob[3] = fmaf(b[2], p01, fmaf(b[3], p11, c[0] * p21));
        oc[0] = fmaf(b[2], p02, fmaf(b[3], p12, c[0] * p22));
        oc[1] = fmaf(c[1], p00, fmaf(c[2], p10, c[3] * p20));
        oc[2] = fmaf(c[1], p01, fmaf(c[2], p11, c[3] * p21));
        oc[3] = fmaf(c[1], p02, fmaf(c[2], p12, c[3] * p22));
        vf4* q = o4 + 3 * (base + k * BLOCK + tid);
        q[0] = oa; q[1] = ob; q[2] = oc;
    }
}

extern "C" void kernel_launch(void* const* d_in, const int* in_sizes, int n_in,
                              void* d_out, int out_size, void* d_ws, size_t ws_size,
                              hipStream_t stream) {
    const float* x = (const float*)d_in[0];
    const float* W = (const float*)d_in[1];
    float* out = (float*)d_out;
    (void)d_ws; (void)ws_size;

    // 2048 blocks x 256 threads x 4 units x 4 rows = 8388608 rows: exact fit
    deep_linear<<<GRID, BLOCK, 0, stream>>>(W, (const vf4*)x, (vf4*)out);
}